// Round 1
// baseline (838.385 us; speedup 1.0000x reference)
//
#include <hip/hip_runtime.h>

// GRU scan: B=2048, T=2048, D=3, H=32. out[b,t] = h_new[b,t][0].
// Mapping: 32 lanes per batch element (lane j owns hidden unit j).
// 64-thread blocks = 2 batch elements per wave; grid 1024 blocks = 1 wave/SIMD.
// Per step: h all-gather via LDS (uniform-address broadcast reads), 96 FMAs
// (3 independent chains), exp/rcp-based gates. fp32 throughout.

#define GRU_B 2048
#define GRU_T 2048
#define GRU_D 3
#define GRU_H 32
#define CHUNK 32  // timesteps per x-staging chunk (32 lanes * 3 floats = 96 = 32 steps)

__device__ __forceinline__ float fast_sigmoid(float x) {
    float e = __expf(-x);                          // v_mul(log2e) + v_exp
    return __builtin_amdgcn_rcpf(1.0f + e);        // ~1 ulp; e=inf -> 0 (correct limit)
}

__device__ __forceinline__ float fast_tanh(float x) {
    float e = __expf(2.0f * x);                    // overflow -> inf -> tanh=1 (correct)
    return 1.0f - 2.0f * __builtin_amdgcn_rcpf(e + 1.0f);
}

__global__ __launch_bounds__(64) void gru_scan_kernel(
    const float* __restrict__ inp,     // [B, T, D]
    const float* __restrict__ w_ih,    // [3H, D]
    const float* __restrict__ w_hh,    // [3H, H]
    const float* __restrict__ bias,    // [3H]
    const float* __restrict__ bias_n,  // [H]
    float* __restrict__ out)           // [B, T]
{
    __shared__ __align__(16) float h_lds[2][GRU_H];
    __shared__ float x_lds[2][CHUNK * GRU_D];

    const int lane = threadIdx.x & 31;   // hidden unit j
    const int grp  = threadIdx.x >> 5;   // which batch element within the wave
    const int b    = blockIdx.x * 2 + grp;

    // ---- one-time weight load into registers ----
    // lane j needs W_hh rows j (reset), H+j (update), 2H+j (new); each row = 32 floats = 128B aligned.
    float wr[GRU_H], wz[GRU_H], wn[GRU_H];
    {
        const float4* r0 = (const float4*)(w_hh + (size_t)lane * GRU_H);
        const float4* r1 = (const float4*)(w_hh + (size_t)(GRU_H + lane) * GRU_H);
        const float4* r2 = (const float4*)(w_hh + (size_t)(2 * GRU_H + lane) * GRU_H);
#pragma unroll
        for (int q = 0; q < GRU_H / 4; ++q) {
            float4 a = r0[q];
            float4 c = r1[q];
            float4 d = r2[q];
            wr[4*q+0] = a.x; wr[4*q+1] = a.y; wr[4*q+2] = a.z; wr[4*q+3] = a.w;
            wz[4*q+0] = c.x; wz[4*q+1] = c.y; wz[4*q+2] = c.z; wz[4*q+3] = c.w;
            wn[4*q+0] = d.x; wn[4*q+1] = d.y; wn[4*q+2] = d.z; wn[4*q+3] = d.w;
        }
    }
    float wir[GRU_D], wiz[GRU_D], win[GRU_D];
#pragma unroll
    for (int d = 0; d < GRU_D; ++d) {
        wir[d] = w_ih[(size_t)lane * GRU_D + d];
        wiz[d] = w_ih[(size_t)(GRU_H + lane) * GRU_D + d];
        win[d] = w_ih[(size_t)(2 * GRU_H + lane) * GRU_D + d];
    }
    const float br = bias[lane];
    const float bz = bias[GRU_H + lane];
    const float ba = bias[2 * GRU_H + lane];
    const float bn = bias_n[lane];

    const float* xb = inp + (size_t)b * GRU_T * GRU_D;
    float*       ob = out + (size_t)b * GRU_T;

    float h = 0.0f;        // own hidden unit value
    float outreg = 0.0f;   // captured output for this lane's timestep within the chunk

    h_lds[grp][lane] = 0.0f;
    __syncthreads();

    for (int c = 0; c < GRU_T / CHUNK; ++c) {
        // ---- stage x for this chunk: 96 contiguous floats per batch element, coalesced ----
        {
            const int base = c * (CHUNK * GRU_D);
            float s0 = xb[base + lane];
            float s1 = xb[base + 32 + lane];
            float s2 = xb[base + 64 + lane];
            x_lds[grp][lane]      = s0;
            x_lds[grp][lane + 32] = s1;
            x_lds[grp][lane + 64] = s2;
        }
        __syncthreads();

#pragma unroll 4
        for (int s = 0; s < CHUNK; ++s) {
            // ---- all-gather h for this group (uniform-address broadcast reads) ----
            float hk[GRU_H];
            {
                const float4* hv = (const float4*)(&h_lds[grp][0]);
#pragma unroll
                for (int q = 0; q < GRU_H / 4; ++q) {
                    float4 v = hv[q];
                    hk[4*q+0] = v.x; hk[4*q+1] = v.y; hk[4*q+2] = v.z; hk[4*q+3] = v.w;
                }
            }
            const float x0 = x_lds[grp][3 * s + 0];
            const float x1 = x_lds[grp][3 * s + 1];
            const float x2 = x_lds[grp][3 * s + 2];

            // input gates (+ bias)
            float ar = br + wir[0] * x0 + wir[1] * x1 + wir[2] * x2;
            float az = bz + wiz[0] * x0 + wiz[1] * x1 + wiz[2] * x2;
            float an = ba + win[0] * x0 + win[1] * x1 + win[2] * x2;

            // hidden gates: 3 independent 32-deep FMA chains
            float gr = 0.0f, gz = 0.0f, gn = 0.0f;
#pragma unroll
            for (int k = 0; k < GRU_H; ++k) {
                gr += wr[k] * hk[k];
                gz += wz[k] * hk[k];
                gn += wn[k] * hk[k];
            }

            float rg = fast_sigmoid(ar + gr);
            float zg = fast_sigmoid(az + gz);
            float ng = fast_tanh(an + bn + rg * gn);
            float hnew = ng + zg * (h - ng);   // (1-z)*n + z*h

            // output capture: hk[0] is h[0] BEFORE this step = output of step s-1.
            // Lane l keeps the output of chunk-step l (captured at step l+1).
            if (lane == s - 1) outreg = hk[0];

            h = hnew;
            h_lds[grp][lane] = h;
            __syncthreads();   // RAW: make h_new visible for next step's gather
        }

        // last step's h[0] (output of chunk-step 31) via direct LDS read
        {
            float h0 = h_lds[grp][0];
            if (lane == 31) outreg = h0;
        }
        // coalesced store: 32 consecutive outputs per batch element
        ob[c * CHUNK + lane] = outreg;
    }
}

extern "C" void kernel_launch(void* const* d_in, const int* in_sizes, int n_in,
                              void* d_out, int out_size, void* d_ws, size_t ws_size,
                              hipStream_t stream) {
    const float* inp    = (const float*)d_in[0];
    const float* w_ih   = (const float*)d_in[1];
    const float* w_hh   = (const float*)d_in[2];
    const float* bias   = (const float*)d_in[3];
    const float* bias_n = (const float*)d_in[4];
    float* out = (float*)d_out;

    dim3 grid(GRU_B / 2);
    dim3 block(64);
    gru_scan_kernel<<<grid, block, 0, stream>>>(inp, w_ih, w_hh, bias, bias_n, out);
}

// Round 2
// 796.240 us; speedup vs baseline: 1.0529x; 1.0529x over previous
//
#include <hip/hip_runtime.h>

// GRU scan: B=2048, T=2048, D=3, H=32. out[b,t] = h_new[b,t][0].
// Round-2 mapping: ONE batch element per 64-lane wave (1 block = 1 wave).
// Lanes j and j+32 both own hidden unit j; each holds HALF the K-reduction
// weights (16 per gate, 48 VGPRs total) -> no AGPR shadowing (round-1 lesson:
// 96 weight regs forced accvgpr traffic that doubled VALU issue).
// Partial dot-products combined via ds_bpermute(lane^32). Grid = 2048 waves
// = 2 waves/SIMD for latency hiding.

#define GRU_B 2048
#define GRU_T 2048
#define GRU_D 3
#define GRU_H 32
#define CHUNK 32  // timesteps per x-staging chunk (32*3 = 96 floats)

__device__ __forceinline__ float fast_sigmoid(float x) {
    float e = __expf(-x);                       // v_mul(log2e)+v_exp
    return __builtin_amdgcn_rcpf(1.0f + e);     // e=inf -> 0 (correct limit)
}
__device__ __forceinline__ float fast_tanh(float x) {
    float e = __expf(2.0f * x);                 // overflow -> inf -> tanh=1
    return 1.0f - 2.0f * __builtin_amdgcn_rcpf(e + 1.0f);
}
__device__ __forceinline__ float xor32(float v, int paddr) {
    return __int_as_float(__builtin_amdgcn_ds_bpermute(paddr, __float_as_int(v)));
}

__global__ __launch_bounds__(64, 2) void gru_scan_kernel(
    const float* __restrict__ inp,     // [B, T, D]
    const float* __restrict__ w_ih,    // [3H, D]
    const float* __restrict__ w_hh,    // [3H, H]
    const float* __restrict__ bias,    // [3H]
    const float* __restrict__ bias_n,  // [H]
    float* __restrict__ out)           // [B, T]
{
    // h2: two mirrored copies of h so both halves write/read unpredicated,
    // conflict-free (copy0 = lanes 0..31, copy1 = lanes 32..63).
    __shared__ __align__(16) float h2[2 * GRU_H];
    __shared__ __align__(16) float x_lds[CHUNK * GRU_D];

    const int lane = threadIdx.x;        // 0..63
    const int unit = lane & 31;          // hidden unit owned
    const int half = lane >> 5;          // K-half: 0 -> k 0..15, 1 -> k 16..31
    const int b    = blockIdx.x;
    const int paddr = (lane ^ 32) << 2;  // bpermute byte addr (hoisted)

    // ---- one-time weight load: 16 K-elems per gate per lane ----
    float wr[16], wz[16], wn[16];
    {
        const float4* pr = (const float4*)(w_hh + (size_t)unit * GRU_H + half * 16);
        const float4* pz = (const float4*)(w_hh + (size_t)(GRU_H + unit) * GRU_H + half * 16);
        const float4* pn = (const float4*)(w_hh + (size_t)(2 * GRU_H + unit) * GRU_H + half * 16);
#pragma unroll
        for (int q = 0; q < 4; ++q) {
            float4 a = pr[q], c = pz[q], d = pn[q];
            wr[4*q+0]=a.x; wr[4*q+1]=a.y; wr[4*q+2]=a.z; wr[4*q+3]=a.w;
            wz[4*q+0]=c.x; wz[4*q+1]=c.y; wz[4*q+2]=c.z; wz[4*q+3]=c.w;
            wn[4*q+0]=d.x; wn[4*q+1]=d.y; wn[4*q+2]=d.z; wn[4*q+3]=d.w;
        }
    }
    float wir[GRU_D], wiz[GRU_D], win[GRU_D];
#pragma unroll
    for (int d = 0; d < GRU_D; ++d) {
        wir[d] = w_ih[(size_t)unit * GRU_D + d];
        wiz[d] = w_ih[(size_t)(GRU_H + unit) * GRU_D + d];
        win[d] = w_ih[(size_t)(2 * GRU_H + unit) * GRU_D + d];
    }
    const float br = bias[unit];
    const float bz = bias[GRU_H + unit];
    const float ba = bias[2 * GRU_H + unit];
    const float bn = bias_n[unit];

    const float* xb = inp + (size_t)b * GRU_T * GRU_D;
    float*       ob = out + (size_t)b * GRU_T;

    float h = 0.0f;       // own unit's hidden value (replicated in both halves)
    float outreg = 0.0f;  // chunk-local captured output (lane l <- step l)

    h2[half * GRU_H + unit] = 0.0f;
    __syncthreads();

    // gather base: half0 reads copy0 units 0..15 (floats 0..15);
    // half1 reads copy1 units 16..31 (floats 48..63). 2 distinct addrs -> free.
    const float4* hv = (const float4*)(h2 + 48 * half);

    for (int c = 0; c < GRU_T / CHUNK; ++c) {
        // ---- stage x chunk: 96 contiguous floats, coalesced ----
        {
            const int base = c * (CHUNK * GRU_D);
            x_lds[lane] = xb[base + lane];
            if (lane < CHUNK * GRU_D - 64) x_lds[64 + lane] = xb[base + 64 + lane];
        }
        __syncthreads();

#pragma unroll 4
        for (int s = 0; s < CHUNK; ++s) {
            // h all-gather: 4 x ds_read_b128, uniform-per-half (broadcast)
            float hk[16];
#pragma unroll
            for (int q = 0; q < 4; ++q) {
                float4 v = hv[q];
                hk[4*q+0]=v.x; hk[4*q+1]=v.y; hk[4*q+2]=v.z; hk[4*q+3]=v.w;
            }
            const float x0 = x_lds[3 * s + 0];
            const float x1 = x_lds[3 * s + 1];
            const float x2 = x_lds[3 * s + 2];

            // input gates (+bias), same in both halves
            float ar = fmaf(wir[2], x2, fmaf(wir[1], x1, fmaf(wir[0], x0, br)));
            float az = fmaf(wiz[2], x2, fmaf(wiz[1], x1, fmaf(wiz[0], x0, bz)));
            float an = fmaf(win[2], x2, fmaf(win[1], x1, fmaf(win[0], x0, ba)));

            // half K-reduction: 3 independent 16-deep FMA chains
            float gr = 0.0f, gz = 0.0f, gn = 0.0f;
#pragma unroll
            for (int k = 0; k < 16; ++k) {
                gr = fmaf(wr[k], hk[k], gr);
                gz = fmaf(wz[k], hk[k], gz);
                gn = fmaf(wn[k], hk[k], gn);
            }
            // combine halves (lane^32) -> full dot products in both halves
            gr += xor32(gr, paddr);
            gz += xor32(gz, paddr);
            gn += xor32(gn, paddr);

            const float rg = fast_sigmoid(ar + gr);
            const float zg = fast_sigmoid(az + gz);
            const float ng = fast_tanh(an + bn + rg * gn);
            const float hnew = fmaf(zg, h - ng, ng);  // (1-z)*n + z*h

            // output capture: hk[0] (half0 lanes) is h[0] BEFORE this step
            // = output of chunk-step s-1; lane s-1 keeps it.
            if (lane == s - 1) outreg = hk[0];

            h = hnew;
            h2[half * GRU_H + unit] = h;
            __syncthreads();  // 1-wave block: compiles to waitcnt (barrier elided)
        }

        // step-31 output: h[0] after last step, via direct LDS read
        {
            const float h0 = h2[0];
            if (lane == CHUNK - 1) outreg = h0;
        }
        if (lane < CHUNK) ob[c * CHUNK + lane] = outreg;  // coalesced 128B store
    }
}

extern "C" void kernel_launch(void* const* d_in, const int* in_sizes, int n_in,
                              void* d_out, int out_size, void* d_ws, size_t ws_size,
                              hipStream_t stream) {
    const float* inp    = (const float*)d_in[0];
    const float* w_ih   = (const float*)d_in[1];
    const float* w_hh   = (const float*)d_in[2];
    const float* bias   = (const float*)d_in[3];
    const float* bias_n = (const float*)d_in[4];
    float* out = (float*)d_out;

    dim3 grid(GRU_B);
    dim3 block(64);
    gru_scan_kernel<<<grid, block, 0, stream>>>(inp, w_ih, w_hh, bias, bias_n, out);
}

// Round 3
// 708.242 us; speedup vs baseline: 1.1838x; 1.1242x over previous
//
#include <hip/hip_runtime.h>

// GRU scan: B=2048, T=2048, D=3, H=32. out[b,t] = h_new[b,t][0].
// Round-3: r2 skeleton (1 batch elem per 64-lane wave, unit x K-half split,
// 2048 waves = 2/SIMD) with two issue-count cuts:
//  (a) no s_barrier: single-wave workgroup + same-wave DS program order;
//      h-exchange ordered by s_waitcnt lgkmcnt(0) only -> vmcnt stays free,
//      x staging loads / out stores remain in flight across steps.
//  (b) sigma-split: half0 computes r's sigmoid while half1 computes z's in the
//      same instruction stream (gate row = unit + 32*half); one bpermute swaps
//      z to half0. Trans ops 6->4 per step, input FMAs 9->6.

#define GRU_B 2048
#define GRU_T 2048
#define GRU_D 3
#define GRU_H 32
#define CHUNK 32  // timesteps per x-staging chunk (32*3 = 96 floats)

// s_waitcnt imm: lgkmcnt(0), vmcnt=63 (no wait), expcnt=7 (no wait)
#define WAIT_LGKM0 0xC07F

__device__ __forceinline__ float fast_sigmoid(float x) {
    float e = __expf(-x);                       // v_mul(log2e)+v_exp
    return __builtin_amdgcn_rcpf(1.0f + e);     // e=inf -> 0 (correct limit)
}
__device__ __forceinline__ float fast_tanh(float x) {
    float e = __expf(2.0f * x);                 // overflow -> inf -> tanh=1
    return 1.0f - 2.0f * __builtin_amdgcn_rcpf(e + 1.0f);
}
__device__ __forceinline__ float xor32(float v, int paddr) {
    return __int_as_float(__builtin_amdgcn_ds_bpermute(paddr, __float_as_int(v)));
}

__global__ __launch_bounds__(64, 2) void gru_scan_kernel(
    const float* __restrict__ inp,     // [B, T, D]
    const float* __restrict__ w_ih,    // [3H, D]
    const float* __restrict__ w_hh,    // [3H, H]
    const float* __restrict__ bias,    // [3H]
    const float* __restrict__ bias_n,  // [H]
    float* __restrict__ out)           // [B, T]
{
    // h2 layout (floats): [0..31] copy0, [32..63] copy1, [64..127] half1 dump.
    __shared__ __align__(16) float h2[4 * GRU_H];
    __shared__ __align__(16) float x_lds[CHUNK * GRU_D];

    const int lane  = threadIdx.x;       // 0..63
    const int unit  = lane & 31;         // hidden unit owned
    const int half  = lane >> 5;         // K-half: 0 -> k 0..15, 1 -> k 16..31
    const int b     = blockIdx.x;
    const int paddr = (lane ^ 32) << 2;  // bpermute byte addr (hoisted)

    // Gate-row assignment for the sigma-split:
    //  rowA = my sigmoid gate (r for half0, z for half1)
    //  rowB = the other sigmoid gate (partial computed only to SEND)
    //  rowC = n gate
    const int rowA = unit + 32 * half;
    const int rowB = unit + 32 * (1 - half);
    const int rowC = 2 * GRU_H + unit;
    const int kofs = 16 * half;          // my K-half columns

    float wa[16], wb[16], wc[16];
    {
        const float4* pa = (const float4*)(w_hh + (size_t)rowA * GRU_H + kofs);
        const float4* pb = (const float4*)(w_hh + (size_t)rowB * GRU_H + kofs);
        const float4* pc = (const float4*)(w_hh + (size_t)rowC * GRU_H + kofs);
#pragma unroll
        for (int q = 0; q < 4; ++q) {
            float4 A = pa[q], Bv = pb[q], Cv = pc[q];
            wa[4*q+0]=A.x;  wa[4*q+1]=A.y;  wa[4*q+2]=A.z;  wa[4*q+3]=A.w;
            wb[4*q+0]=Bv.x; wb[4*q+1]=Bv.y; wb[4*q+2]=Bv.z; wb[4*q+3]=Bv.w;
            wc[4*q+0]=Cv.x; wc[4*q+1]=Cv.y; wc[4*q+2]=Cv.z; wc[4*q+3]=Cv.w;
        }
    }
    float wia[GRU_D], wic[GRU_D];
#pragma unroll
    for (int d = 0; d < GRU_D; ++d) {
        wia[d] = w_ih[(size_t)rowA * GRU_D + d];
        wic[d] = w_ih[(size_t)rowC * GRU_D + d];
    }
    const float bA = bias[rowA];                    // r-bias (half0) / z-bias (half1)
    const float bC = bias[rowC] + bias_n[unit];     // n-gate bias, bias_n folded in

    const float* xb = inp + (size_t)b * GRU_T * GRU_D;
    float*       ob = out + (size_t)b * GRU_T;

    float h = 0.0f;       // own unit's h (valid trajectory in half0; finite in half1)
    float outreg = 0.0f;  // chunk-local captured output (lane t <- step t)

    h2[lane] = 0.0f;      // zero copy0 + copy1
    __builtin_amdgcn_s_waitcnt(WAIT_LGKM0);

    // gather base: half0 reads copy0 units 0..15 (floats 0..15);
    // half1 reads copy1 units 16..31 (floats 48..63).
    const float4* hv = (const float4*)(h2 + 48 * half);
    // write base: half0 -> copies (unit, unit+32); half1 -> dump (64+unit, 96+unit)
    const int wbase = unit + 64 * half;

    for (int c = 0; c < GRU_T / CHUNK; ++c) {
        // ---- stage x chunk: 96 contiguous floats, coalesced ----
        {
            const int base = c * (CHUNK * GRU_D);
            x_lds[lane] = xb[base + lane];
            if (lane < CHUNK * GRU_D - 64) x_lds[64 + lane] = xb[base + 64 + lane];
        }
        __builtin_amdgcn_s_waitcnt(WAIT_LGKM0);  // x_lds visible (same-wave order)

#pragma unroll 8
        for (int s = 0; s < CHUNK; ++s) {
            // h all-gather: 4 x ds_read_b128, uniform-per-half (broadcast)
            float hk[16];
#pragma unroll
            for (int q = 0; q < 4; ++q) {
                float4 v = hv[q];
                hk[4*q+0]=v.x; hk[4*q+1]=v.y; hk[4*q+2]=v.z; hk[4*q+3]=v.w;
            }
            const float x0 = x_lds[3 * s + 0];
            const float x1 = x_lds[3 * s + 1];
            const float x2 = x_lds[3 * s + 2];

            // input projections: my sigmoid gate + n gate (6 FMAs)
            const float aM = fmaf(wia[2], x2, fmaf(wia[1], x1, fmaf(wia[0], x0, bA)));
            const float aN = fmaf(wic[2], x2, fmaf(wic[1], x1, fmaf(wic[0], x0, bC)));

            // K-half partials: my gate (A), other gate (B, to send), n gate (C)
            float A = 0.0f, Bp = 0.0f, Cp = 0.0f;
#pragma unroll
            for (int k = 0; k < 16; ++k) {
                A  = fmaf(wa[k], hk[k], A);
                Bp = fmaf(wb[k], hk[k], Bp);
                Cp = fmaf(wc[k], hk[k], Cp);
            }
            // combine: my full sigmoid-gate sum = own partial + other's sent partial
            const float gM = A  + xor32(Bp, paddr);
            const float gN = Cp + xor32(Cp, paddr);

            const float sg  = fast_sigmoid(aM + gM);  // half0: r, half1: z
            const float zsw = xor32(sg, paddr);       // half0: z (half1: r, unused)
            const float n   = fast_tanh(fmaf(sg, gN, aN));   // valid in half0
            const float hnew = fmaf(zsw, h - n, n);          // (1-z)*n + z*h, half0

            // hk[0] in half0 = h[0] BEFORE this step = output of step s-1
            if (lane == s - 1) outreg = hk[0];

            h = hnew;
            h2[wbase]      = h;   // half0: copy0; half1: dump
            h2[wbase + 32] = h;   // half0: copy1; half1: dump
            __builtin_amdgcn_s_waitcnt(WAIT_LGKM0);  // writes complete before next gather
        }

        // step-31 output: h[0] after last step
        {
            const float h0 = h2[0];
            if (lane == CHUNK - 1) outreg = h0;
        }
        if (lane < CHUNK) ob[c * CHUNK + lane] = outreg;  // coalesced 128B store
    }
}

extern "C" void kernel_launch(void* const* d_in, const int* in_sizes, int n_in,
                              void* d_out, int out_size, void* d_ws, size_t ws_size,
                              hipStream_t stream) {
    const float* inp    = (const float*)d_in[0];
    const float* w_ih   = (const float*)d_in[1];
    const float* w_hh   = (const float*)d_in[2];
    const float* bias   = (const float*)d_in[3];
    const float* bias_n = (const float*)d_in[4];
    float* out = (float*)d_out;

    dim3 grid(GRU_B);
    dim3 block(64);
    gru_scan_kernel<<<grid, block, 0, stream>>>(inp, w_ih, w_hh, bias, bias_n, out);
}